// Round 6
// baseline (362.955 us; speedup 1.0000x reference)
//
#include <hip/hip_runtime.h>
#include <math.h>

#define B_DIM 8
#define N_DIM 2048
#define F_IN 256
#define F_OUT 128
#define ALPHA 0.2f
#define KPAD 136
#define LSTR 132                 // LDS acc row stride (pad: q*4*132 % 32 banks != 0)

typedef __attribute__((ext_vector_type(8))) short short8;
typedef __attribute__((ext_vector_type(4))) float floatx4;

static __device__ __forceinline__ unsigned short f2bf(float f) {
    unsigned u = __float_as_uint(f);
    u += 0x7fff + ((u >> 16) & 1);   // RNE
    return (unsigned short)(u >> 16);
}
static __device__ __forceinline__ float bf2f(unsigned short s) {
    return __uint_as_float((unsigned)s << 16);
}
// monotone fp32 <-> uint32 map for atomicMax
static __device__ __forceinline__ unsigned fmap(float f) {
    int b = __float_as_int(f);
    return (unsigned)(b ^ ((b >> 31) | 0x80000000));
}
static __device__ __forceinline__ float funmap(unsigned u) {
    return __uint_as_float((u & 0x80000000u) ? (int)(u ^ 0x80000000u) : ~(int)u);
}

// ---------------- Kernel 1: WhT(bf16) = (X @ W)^T via MFMA, fused s1/s2 + s2max ----------------
// 256 blocks x 256 thr. Wave = 16 rows x 128 cols. WhT layout: [b][col][n] bf16.
__global__ __launch_bounds__(256) void gemm_xw(const float* __restrict__ X,
                                               const float* __restrict__ W,
                                               const float* __restrict__ avec,
                                               unsigned short* __restrict__ WhT,
                                               float* __restrict__ s1,
                                               float* __restrict__ s2,
                                               unsigned* __restrict__ s2max_u) {
    __shared__ unsigned short Wt[F_OUT][KPAD];  // 34 KB
    const int t = threadIdx.x;
    const int lane = t & 63, wave = t >> 6;
    const int m = lane & 15, q = lane >> 4;
    const int row0 = blockIdx.x * 64 + wave * 16;

    floatx4 acc[8];
#pragma unroll
    for (int nt = 0; nt < 8; nt++) acc[nt] = (floatx4){0.f, 0.f, 0.f, 0.f};

    const int n0 = (t & 31) * 4;
    const int kb = t >> 5;

    for (int half = 0; half < 2; half++) {
        const float* Wp = W + (size_t)(half * 128 + kb) * F_OUT + n0;
#pragma unroll
        for (int i = 0; i < 16; i++) {
            float4 w = *(const float4*)(Wp + (size_t)i * 8 * F_OUT);
            int kk = kb + i * 8;
            Wt[n0 + 0][kk] = f2bf(w.x);
            Wt[n0 + 1][kk] = f2bf(w.y);
            Wt[n0 + 2][kk] = f2bf(w.z);
            Wt[n0 + 3][kk] = f2bf(w.w);
        }
        __syncthreads();

        const float* xrow = X + (size_t)(row0 + m) * F_IN + half * 128 + q * 8;
        float4 xr[8];
#pragma unroll
        for (int kt = 0; kt < 4; kt++) {
            xr[2 * kt] = *(const float4*)(xrow + kt * 32);
            xr[2 * kt + 1] = *(const float4*)(xrow + kt * 32 + 4);
        }
#pragma unroll
        for (int kt = 0; kt < 4; kt++) {
            union { unsigned short u[8]; short8 v; } af;
            float tmp[8] = {xr[2 * kt].x, xr[2 * kt].y, xr[2 * kt].z, xr[2 * kt].w,
                            xr[2 * kt + 1].x, xr[2 * kt + 1].y, xr[2 * kt + 1].z, xr[2 * kt + 1].w};
#pragma unroll
            for (int j = 0; j < 8; j++) af.u[j] = f2bf(tmp[j]);
#pragma unroll
            for (int nt = 0; nt < 8; nt++) {
                short8 bv = *(const short8*)&Wt[nt * 16 + m][kt * 32 + q * 8];
                acc[nt] = __builtin_amdgcn_mfma_f32_16x16x32_bf16(af.v, bv, acc[nt], 0, 0, 0);
            }
        }
        __syncthreads();
    }

    // ---- store WhT[b][col][n] bf16 ----
    const int b = row0 >> 11;
    unsigned short* WTb = WhT + (size_t)b * F_OUT * N_DIM;
#pragma unroll
    for (int nt = 0; nt < 8; nt++) {
#pragma unroll
        for (int r = 0; r < 4; r++) {
            int nloc = (row0 & 2047) + q * 4 + r;
            WTb[(size_t)(nt * 16 + m) * N_DIM + nloc] = f2bf(acc[nt][r]);
        }
    }
    // ---- fused s1/s2 + per-batch s2 max ----
    float a1v[8], a2v[8];
#pragma unroll
    for (int nt = 0; nt < 8; nt++) {
        a1v[nt] = avec[nt * 16 + m];
        a2v[nt] = avec[F_OUT + nt * 16 + m];
    }
    float wmax = -1e30f;
#pragma unroll
    for (int r = 0; r < 4; r++) {
        float v1 = 0.f, v2 = 0.f;
#pragma unroll
        for (int nt = 0; nt < 8; nt++) {
            v1 = fmaf(acc[nt][r], a1v[nt], v1);
            v2 = fmaf(acc[nt][r], a2v[nt], v2);
        }
#pragma unroll
        for (int mk = 8; mk >= 1; mk >>= 1) {
            v1 += __shfl_xor(v1, mk, 64);
            v2 += __shfl_xor(v2, mk, 64);
        }
        if (m == 0) {
            int row = row0 + q * 4 + r;
            s1[row] = v1;
            s2[row] = v2;
        }
        wmax = fmaxf(wmax, v2);
    }
    wmax = fmaxf(wmax, __shfl_xor(wmax, 16, 64));
    wmax = fmaxf(wmax, __shfl_xor(wmax, 32, 64));
    if (lane == 0) atomicMax(&s2max_u[b], fmap(wmax));
}

// ---------------- Kernel 2: masked-dense flash GAT via MFMA ----------------
// Grid 1024 blocks x 512 thr (8 waves). Block = 16 output rows; wave w covers
// n in [w*256, w*256+256). p = A * exp(leaky(s1+s2) - shift) built in-register,
// fed to mfma vs WhT fragments loaded straight from global (L2-resident).
// Partials combined via LDS atomicAdd. Uniform control flow, no ballots.
__global__ __launch_bounds__(512) void attn_mm(const float* __restrict__ A,
                                               const unsigned short* __restrict__ WhT,
                                               const float* __restrict__ s1,
                                               const float* __restrict__ s2,
                                               const unsigned* __restrict__ s2max_u,
                                               float* __restrict__ out) {
    __shared__ float lred[16 * LSTR + 16];  // acc[16][LSTR] + l[16]

    const int t = threadIdx.x;
    const int lane = t & 63, wave = t >> 6;
    const int m = lane & 15, q = lane >> 4;
    const int row0 = blockIdx.x * 16;
    const int b = row0 >> 11;
    const int nbase = wave * 256;

    // zero LDS (barrier deferred to after the k-loop)
    for (int i = t; i < 16 * LSTR + 16; i += 512) lred[i] = 0.f;

    const float s1m = s1[row0 + m];
    const float s2mx = funmap(s2max_u[b]);
    const float xs = s1m + s2mx;
    const float shift = fmaxf(xs, ALPHA * xs);  // >= max_n leaky(s1m + s2n)

    const float* Ar = A + (size_t)(row0 + m) * N_DIM + nbase + q * 8;
    const float* s2p = s2 + (size_t)b * N_DIM + nbase + q * 8;
    const unsigned short* WT = WhT + (size_t)b * F_OUT * N_DIM + nbase + q * 8;

    floatx4 acc[8];
#pragma unroll
    for (int nt = 0; nt < 8; nt++) acc[nt] = (floatx4){0.f, 0.f, 0.f, 0.f};
    float lsum = 0.f;

#pragma unroll
    for (int s = 0; s < 8; s++) {
        const int off = s * 32;
        float4 a0 = *(const float4*)(Ar + off);
        float4 a1 = *(const float4*)(Ar + off + 4);
        float4 z0 = *(const float4*)(s2p + off);
        float4 z1 = *(const float4*)(s2p + off + 4);
        float aa[8] = {a0.x, a0.y, a0.z, a0.w, a1.x, a1.y, a1.z, a1.w};
        float zz[8] = {z0.x, z0.y, z0.z, z0.w, z1.x, z1.y, z1.z, z1.w};
        union { unsigned short u[8]; short8 v; } pf;
#pragma unroll
        for (int j = 0; j < 8; j++) {
            float x = s1m + zz[j];
            float e = fmaxf(x, ALPHA * x);
            float p = aa[j] * __expf(e - shift);   // A is exactly 0/1 -> mask
            unsigned short pb = f2bf(p);
            pf.u[j] = pb;
            lsum += bf2f(pb);                       // denom matches MFMA operand
        }
#pragma unroll
        for (int nt = 0; nt < 8; nt++) {
            short8 bv = *(const short8*)(WT + (size_t)(nt * 16 + m) * N_DIM + off);
            acc[nt] = __builtin_amdgcn_mfma_f32_16x16x32_bf16(pf.v, bv, acc[nt], 0, 0, 0);
        }
    }

    // reduce lsum over q (lanes m, m+16, m+32, m+48 share a row)
    lsum += __shfl_xor(lsum, 16, 64);
    lsum += __shfl_xor(lsum, 32, 64);

    __syncthreads();  // zeroing complete
    if (lane < 16) atomicAdd(&lred[16 * LSTR + lane], lsum);
#pragma unroll
    for (int nt = 0; nt < 8; nt++)
#pragma unroll
        for (int r = 0; r < 4; r++)
            atomicAdd(&lred[(q * 4 + r) * LSTR + nt * 16 + m], acc[nt][r]);
    __syncthreads();

    // write out: 512 thr x 4 cols
    {
        int r = t >> 5, c0 = (t & 31) * 4;
        float inv = 1.f / lred[16 * LSTR + r];
        float4 v = *(const float4*)&lred[r * LSTR + c0];
        v.x *= inv; v.y *= inv; v.z *= inv; v.w *= inv;
        *(float4*)&out[(size_t)(row0 + r) * F_OUT + c0] = v;
    }
}

extern "C" void kernel_launch(void* const* d_in, const int* in_sizes, int n_in,
                              void* d_out, int out_size, void* d_ws, size_t ws_size,
                              hipStream_t stream) {
    const float* X = (const float*)d_in[0];
    const float* A = (const float*)d_in[1];
    const float* W = (const float*)d_in[2];
    const float* avec = (const float*)d_in[3];
    float* out = (float*)d_out;

    unsigned short* WhT = (unsigned short*)d_ws;                       // 4 MB bf16 [8][128][2048]
    float* s1 = (float*)((char*)d_ws + (size_t)B_DIM * F_OUT * N_DIM * 2);
    float* s2 = s1 + B_DIM * N_DIM;
    unsigned* s2max_u = (unsigned*)(s2 + B_DIM * N_DIM);

    hipMemsetAsync(s2max_u, 0, B_DIM * sizeof(unsigned), stream);      // maps to -FLT_MAX
    gemm_xw<<<B_DIM * N_DIM / 64, 256, 0, stream>>>(X, W, avec, WhT, s1, s2, s2max_u);
    attn_mm<<<B_DIM * N_DIM / 16, 512, 0, stream>>>(A, WhT, s1, s2, s2max_u, out);
}

// Round 7
// 261.024 us; speedup vs baseline: 1.3905x; 1.3905x over previous
//
#include <hip/hip_runtime.h>
#include <math.h>

#define B_DIM 8
#define N_DIM 2048
#define F_IN 256
#define F_OUT 128
#define ALPHA 0.2f
#define KPAD 136
#define NT_TILE 128     // n per LDS tile
#define TILES 16
#define BSTR 136        // LDS tile col stride (elems): addr/4 = col*68 -> 4*(col%8) bank spread

typedef __attribute__((ext_vector_type(8))) short short8;
typedef __attribute__((ext_vector_type(4))) float floatx4;

static __device__ __forceinline__ unsigned short f2bf(float f) {
    unsigned u = __float_as_uint(f);
    u += 0x7fff + ((u >> 16) & 1);   // RNE
    return (unsigned short)(u >> 16);
}
static __device__ __forceinline__ float bf2f(unsigned short s) {
    return __uint_as_float((unsigned)s << 16);
}
// monotone fp32 <-> uint32 map for atomicMax (all reals map > 0)
static __device__ __forceinline__ unsigned fmap(float f) {
    int b = __float_as_int(f);
    return (unsigned)(b ^ ((b >> 31) | 0x80000000));
}
static __device__ __forceinline__ float funmap(unsigned u) {
    return __uint_as_float((u & 0x80000000u) ? (int)(u ^ 0x80000000u) : ~(int)u);
}

// ---------------- Kernel 1: WhT(bf16) = (X @ W)^T via MFMA, fused s1/s2 + s2max ----------------
// (unchanged from R6 — validated)
__global__ __launch_bounds__(256) void gemm_xw(const float* __restrict__ X,
                                               const float* __restrict__ W,
                                               const float* __restrict__ avec,
                                               unsigned short* __restrict__ WhT,
                                               float* __restrict__ s1,
                                               float* __restrict__ s2,
                                               unsigned* __restrict__ s2max_u) {
    __shared__ unsigned short Wt[F_OUT][KPAD];  // 34 KB
    const int t = threadIdx.x;
    const int lane = t & 63, wave = t >> 6;
    const int m = lane & 15, q = lane >> 4;
    const int row0 = blockIdx.x * 64 + wave * 16;

    floatx4 acc[8];
#pragma unroll
    for (int nt = 0; nt < 8; nt++) acc[nt] = (floatx4){0.f, 0.f, 0.f, 0.f};

    const int n0 = (t & 31) * 4;
    const int kb = t >> 5;

    for (int half = 0; half < 2; half++) {
        const float* Wp = W + (size_t)(half * 128 + kb) * F_OUT + n0;
#pragma unroll
        for (int i = 0; i < 16; i++) {
            float4 w = *(const float4*)(Wp + (size_t)i * 8 * F_OUT);
            int kk = kb + i * 8;
            Wt[n0 + 0][kk] = f2bf(w.x);
            Wt[n0 + 1][kk] = f2bf(w.y);
            Wt[n0 + 2][kk] = f2bf(w.z);
            Wt[n0 + 3][kk] = f2bf(w.w);
        }
        __syncthreads();

        const float* xrow = X + (size_t)(row0 + m) * F_IN + half * 128 + q * 8;
        float4 xr[8];
#pragma unroll
        for (int kt = 0; kt < 4; kt++) {
            xr[2 * kt] = *(const float4*)(xrow + kt * 32);
            xr[2 * kt + 1] = *(const float4*)(xrow + kt * 32 + 4);
        }
#pragma unroll
        for (int kt = 0; kt < 4; kt++) {
            union { unsigned short u[8]; short8 v; } af;
            float tmp[8] = {xr[2 * kt].x, xr[2 * kt].y, xr[2 * kt].z, xr[2 * kt].w,
                            xr[2 * kt + 1].x, xr[2 * kt + 1].y, xr[2 * kt + 1].z, xr[2 * kt + 1].w};
#pragma unroll
            for (int j = 0; j < 8; j++) af.u[j] = f2bf(tmp[j]);
#pragma unroll
            for (int nt = 0; nt < 8; nt++) {
                short8 bv = *(const short8*)&Wt[nt * 16 + m][kt * 32 + q * 8];
                acc[nt] = __builtin_amdgcn_mfma_f32_16x16x32_bf16(af.v, bv, acc[nt], 0, 0, 0);
            }
        }
        __syncthreads();
    }

    const int b = row0 >> 11;
    unsigned short* WTb = WhT + (size_t)b * F_OUT * N_DIM;
#pragma unroll
    for (int nt = 0; nt < 8; nt++) {
#pragma unroll
        for (int r = 0; r < 4; r++) {
            int nloc = (row0 & 2047) + q * 4 + r;
            WTb[(size_t)(nt * 16 + m) * N_DIM + nloc] = f2bf(acc[nt][r]);
        }
    }
    float a1v[8], a2v[8];
#pragma unroll
    for (int nt = 0; nt < 8; nt++) {
        a1v[nt] = avec[nt * 16 + m];
        a2v[nt] = avec[F_OUT + nt * 16 + m];
    }
    float wmax = -1e30f;
#pragma unroll
    for (int r = 0; r < 4; r++) {
        float v1 = 0.f, v2 = 0.f;
#pragma unroll
        for (int nt = 0; nt < 8; nt++) {
            v1 = fmaf(acc[nt][r], a1v[nt], v1);
            v2 = fmaf(acc[nt][r], a2v[nt], v2);
        }
#pragma unroll
        for (int mk = 8; mk >= 1; mk >>= 1) {
            v1 += __shfl_xor(v1, mk, 64);
            v2 += __shfl_xor(v2, mk, 64);
        }
        if (m == 0) {
            int row = row0 + q * 4 + r;
            s1[row] = v1;
            s2[row] = v2;
        }
        wmax = fmaxf(wmax, v2);
    }
    wmax = fmaxf(wmax, __shfl_xor(wmax, 16, 64));
    wmax = fmaxf(wmax, __shfl_xor(wmax, 32, 64));
    if (lane == 0) atomicMax(&s2max_u[b], fmap(wmax));
}

// ---------------- Kernel 2: masked-dense MFMA, LDS-staged double-buffered tiles ----------------
// 256 blocks x 256 thr (4 waves x 16 rows, no k-split). n swept in 16 tiles of 128.
// WhT tile (128 cols x 128 n bf16) staged in LDS; P built in registers from A stream.
__global__ __launch_bounds__(256) void attn_mm(const float* __restrict__ A,
                                               const unsigned short* __restrict__ WhT,
                                               const float* __restrict__ s1,
                                               const float* __restrict__ s2,
                                               const unsigned* __restrict__ s2max_u,
                                               float* __restrict__ out) {
    __shared__ unsigned short Bs[2][F_OUT][BSTR];  // 69,632 B
    __shared__ float s2l[N_DIM];                   // 8 KB

    const int t = threadIdx.x;
    const int lane = t & 63, wave = t >> 6;
    const int m = lane & 15, q = lane >> 4;
    const int row0 = blockIdx.x * 64;
    const int b = row0 >> 11;
    const unsigned short* WTb = WhT + (size_t)b * F_OUT * N_DIM;

    // stage s2 for this batch (256 thr x 8 floats)
    {
        const float4* sg = (const float4*)(s2 + (size_t)b * N_DIM);
        *(float4*)&s2l[t * 8] = sg[t * 2];
        *(float4*)&s2l[t * 8 + 4] = sg[t * 2 + 1];
    }

    const int myrow = row0 + wave * 16 + m;
    const float s1m = s1[myrow];
    const float s2mx = funmap(s2max_u[b]);
    const float xs = s1m + s2mx;
    const float shift = fmaxf(xs, ALPHA * xs);  // >= max_n leaky(s1m + s2n)
    const float* Arow = A + (size_t)myrow * N_DIM;

    const int g = t & 15, colb = t >> 4;  // staging: granule, col-base

    // preload A regs for tile 0 + stage tile 0
    float4 a_cur[8], a_nxt[8];
#pragma unroll
    for (int c = 0; c < 4; c++) {
        a_cur[2 * c] = *(const float4*)(Arow + c * 32 + q * 8);
        a_cur[2 * c + 1] = *(const float4*)(Arow + c * 32 + q * 8 + 4);
    }
    uint4 sreg[8];
#pragma unroll
    for (int i = 0; i < 8; i++)
        sreg[i] = *(const uint4*)(WTb + (size_t)(colb + i * 16) * N_DIM + g * 8);
#pragma unroll
    for (int i = 0; i < 8; i++)
        *(uint4*)&Bs[0][colb + i * 16][g * 8] = sreg[i];

    floatx4 acc[8];
#pragma unroll
    for (int nt = 0; nt < 8; nt++) acc[nt] = (floatx4){0.f, 0.f, 0.f, 0.f};
    float lsum = 0.f;

    __syncthreads();

    for (int tl = 0; tl < TILES; ++tl) {
        const int cur = tl & 1, nxt = cur ^ 1;
        // issue next-tile loads (A + stage), in flight across P-compute + MFMA
        if (tl + 1 < TILES) {
            const float* An = Arow + (tl + 1) * NT_TILE;
#pragma unroll
            for (int c = 0; c < 4; c++) {
                a_nxt[2 * c] = *(const float4*)(An + c * 32 + q * 8);
                a_nxt[2 * c + 1] = *(const float4*)(An + c * 32 + q * 8 + 4);
            }
            const unsigned short* Wn = WTb + (size_t)(tl + 1) * NT_TILE + g * 8;
#pragma unroll
            for (int i = 0; i < 8; i++)
                sreg[i] = *(const uint4*)(Wn + (size_t)(colb + i * 16) * N_DIM);
        }
        // ---- P fragments from a_cur + s2l ----
        short8 pf[4];
#pragma unroll
        for (int c = 0; c < 4; c++) {
            float4 sa = *(const float4*)&s2l[tl * NT_TILE + c * 32 + q * 8];
            float4 sb = *(const float4*)&s2l[tl * NT_TILE + c * 32 + q * 8 + 4];
            float aa[8] = {a_cur[2 * c].x, a_cur[2 * c].y, a_cur[2 * c].z, a_cur[2 * c].w,
                           a_cur[2 * c + 1].x, a_cur[2 * c + 1].y, a_cur[2 * c + 1].z, a_cur[2 * c + 1].w};
            float zz[8] = {sa.x, sa.y, sa.z, sa.w, sb.x, sb.y, sb.z, sb.w};
            union { unsigned short u[8]; short8 v; } pu;
#pragma unroll
            for (int j = 0; j < 8; j++) {
                float x = s1m + zz[j];
                float e = fmaxf(x, ALPHA * x);
                float p = aa[j] * __expf(e - shift);  // A is exactly 0/1 -> mask
                unsigned short pb = f2bf(p);
                pu.u[j] = pb;
                lsum += bf2f(pb);                      // denom == what MFMA sees
            }
            pf[c] = pu.v;
        }
        // ---- MFMA on Bs[cur] ----
#pragma unroll
        for (int c = 0; c < 4; c++)
#pragma unroll
            for (int nt = 0; nt < 8; nt++) {
                short8 bv = *(const short8*)&Bs[cur][nt * 16 + m][c * 32 + q * 8];
                acc[nt] = __builtin_amdgcn_mfma_f32_16x16x32_bf16(pf[c], bv, acc[nt], 0, 0, 0);
            }
        // ---- commit staged regs to the other buffer ----
        if (tl + 1 < TILES) {
#pragma unroll
            for (int i = 0; i < 8; i++)
                *(uint4*)&Bs[nxt][colb + i * 16][g * 8] = sreg[i];
#pragma unroll
            for (int i = 0; i < 8; i++) a_cur[i] = a_nxt[i];
        }
        __syncthreads();
    }

    // ---- epilogue: denom + normalized stores ----
    lsum += __shfl_xor(lsum, 16, 64);
    lsum += __shfl_xor(lsum, 32, 64);
    const float inv = 1.f / lsum;  // valid for row m on every lane
#pragma unroll
    for (int r = 0; r < 4; r++) {
        float invr = __shfl(inv, q * 4 + r, 64);  // denom of output row q*4+r
        float* orow = out + (size_t)(row0 + wave * 16 + q * 4 + r) * F_OUT + m;
#pragma unroll
        for (int nt = 0; nt < 8; nt++) orow[nt * 16] = acc[nt][r] * invr;
    }
}

extern "C" void kernel_launch(void* const* d_in, const int* in_sizes, int n_in,
                              void* d_out, int out_size, void* d_ws, size_t ws_size,
                              hipStream_t stream) {
    const float* X = (const float*)d_in[0];
    const float* A = (const float*)d_in[1];
    const float* W = (const float*)d_in[2];
    const float* avec = (const float*)d_in[3];
    float* out = (float*)d_out;

    unsigned short* WhT = (unsigned short*)d_ws;                       // 4 MB bf16 [8][128][2048]
    float* s1 = (float*)((char*)d_ws + (size_t)B_DIM * F_OUT * N_DIM * 2);
    float* s2 = s1 + B_DIM * N_DIM;
    unsigned* s2max_u = (unsigned*)(s2 + B_DIM * N_DIM);

    hipMemsetAsync(s2max_u, 0, B_DIM * sizeof(unsigned), stream);      // 0 < fmap(any real)
    gemm_xw<<<B_DIM * N_DIM / 64, 256, 0, stream>>>(X, W, avec, WhT, s1, s2, s2max_u);
    attn_mm<<<B_DIM * N_DIM / 64, 256, 0, stream>>>(A, WhT, s1, s2, s2max_u, out);
}

// Round 8
// 258.933 us; speedup vs baseline: 1.4017x; 1.0081x over previous
//
#include <hip/hip_runtime.h>
#include <math.h>

#define B_DIM 8
#define N_DIM 2048
#define F_IN 256
#define F_OUT 128
#define ALPHA 0.2f
#define KPAD 136
#define NSPLIT 4
#define TPB 4            // tiles (of 128 n) per block
#define PS ((size_t)B_DIM * N_DIM * F_OUT)  // partial-acc ns stride

typedef __attribute__((ext_vector_type(8))) short short8;
typedef __attribute__((ext_vector_type(4))) float floatx4;

static __device__ __forceinline__ unsigned short f2bf(float f) {
    unsigned u = __float_as_uint(f);
    u += 0x7fff + ((u >> 16) & 1);   // RNE
    return (unsigned short)(u >> 16);
}
static __device__ __forceinline__ float bf2f(unsigned short s) {
    return __uint_as_float((unsigned)s << 16);
}
static __device__ __forceinline__ unsigned fmap(float f) {
    int b = __float_as_int(f);
    return (unsigned)(b ^ ((b >> 31) | 0x80000000));
}
static __device__ __forceinline__ float funmap(unsigned u) {
    return __uint_as_float((u & 0x80000000u) ? (int)(u ^ 0x80000000u) : ~(int)u);
}

// ---------------- Kernel 1: WhT(bf16) = (X @ W)^T via MFMA, fused s1/s2 + s2max ----------------
// (unchanged — validated)
__global__ __launch_bounds__(256) void gemm_xw(const float* __restrict__ X,
                                               const float* __restrict__ W,
                                               const float* __restrict__ avec,
                                               unsigned short* __restrict__ WhT,
                                               float* __restrict__ s1,
                                               float* __restrict__ s2,
                                               unsigned* __restrict__ s2max_u) {
    __shared__ unsigned short Wt[F_OUT][KPAD];
    const int t = threadIdx.x;
    const int lane = t & 63, wave = t >> 6;
    const int m = lane & 15, q = lane >> 4;
    const int row0 = blockIdx.x * 64 + wave * 16;

    floatx4 acc[8];
#pragma unroll
    for (int nt = 0; nt < 8; nt++) acc[nt] = (floatx4){0.f, 0.f, 0.f, 0.f};

    const int n0 = (t & 31) * 4;
    const int kb = t >> 5;

    for (int half = 0; half < 2; half++) {
        const float* Wp = W + (size_t)(half * 128 + kb) * F_OUT + n0;
#pragma unroll
        for (int i = 0; i < 16; i++) {
            float4 w = *(const float4*)(Wp + (size_t)i * 8 * F_OUT);
            int kk = kb + i * 8;
            Wt[n0 + 0][kk] = f2bf(w.x);
            Wt[n0 + 1][kk] = f2bf(w.y);
            Wt[n0 + 2][kk] = f2bf(w.z);
            Wt[n0 + 3][kk] = f2bf(w.w);
        }
        __syncthreads();

        const float* xrow = X + (size_t)(row0 + m) * F_IN + half * 128 + q * 8;
        float4 xr[8];
#pragma unroll
        for (int kt = 0; kt < 4; kt++) {
            xr[2 * kt] = *(const float4*)(xrow + kt * 32);
            xr[2 * kt + 1] = *(const float4*)(xrow + kt * 32 + 4);
        }
#pragma unroll
        for (int kt = 0; kt < 4; kt++) {
            union { unsigned short u[8]; short8 v; } af;
            float tmp[8] = {xr[2 * kt].x, xr[2 * kt].y, xr[2 * kt].z, xr[2 * kt].w,
                            xr[2 * kt + 1].x, xr[2 * kt + 1].y, xr[2 * kt + 1].z, xr[2 * kt + 1].w};
#pragma unroll
            for (int j = 0; j < 8; j++) af.u[j] = f2bf(tmp[j]);
#pragma unroll
            for (int nt = 0; nt < 8; nt++) {
                short8 bv = *(const short8*)&Wt[nt * 16 + m][kt * 32 + q * 8];
                acc[nt] = __builtin_amdgcn_mfma_f32_16x16x32_bf16(af.v, bv, acc[nt], 0, 0, 0);
            }
        }
        __syncthreads();
    }

    const int b = row0 >> 11;
    unsigned short* WTb = WhT + (size_t)b * F_OUT * N_DIM;
#pragma unroll
    for (int nt = 0; nt < 8; nt++) {
#pragma unroll
        for (int r = 0; r < 4; r++) {
            int nloc = (row0 & 2047) + q * 4 + r;
            WTb[(size_t)(nt * 16 + m) * N_DIM + nloc] = f2bf(acc[nt][r]);
        }
    }
    float a1v[8], a2v[8];
#pragma unroll
    for (int nt = 0; nt < 8; nt++) {
        a1v[nt] = avec[nt * 16 + m];
        a2v[nt] = avec[F_OUT + nt * 16 + m];
    }
    float wmax = -1e30f;
#pragma unroll
    for (int r = 0; r < 4; r++) {
        float v1 = 0.f, v2 = 0.f;
#pragma unroll
        for (int nt = 0; nt < 8; nt++) {
            v1 = fmaf(acc[nt][r], a1v[nt], v1);
            v2 = fmaf(acc[nt][r], a2v[nt], v2);
        }
#pragma unroll
        for (int mk = 8; mk >= 1; mk >>= 1) {
            v1 += __shfl_xor(v1, mk, 64);
            v2 += __shfl_xor(v2, mk, 64);
        }
        if (m == 0) {
            int row = row0 + q * 4 + r;
            s1[row] = v1;
            s2[row] = v2;
        }
        wmax = fmaxf(wmax, v2);
    }
    wmax = fmaxf(wmax, __shfl_xor(wmax, 16, 64));
    wmax = fmaxf(wmax, __shfl_xor(wmax, 32, 64));
    if (lane == 0) atomicMax(&s2max_u[b], fmap(wmax));
}

// ---------------- Kernel 2: masked-dense MFMA, n-split, fragment-major LDS ----------------
// Grid 1024 = 256 row-groups x 4 n-splits (ns-major for L2 tile sharing).
// Block: 256 thr / 4 waves / 64 rows; 4 tiles of 128 n. Partials to pacc/plsum.
// LDS tile stored fragment-major: granule f=(nt*4+c)*64+lane -> stride-1 b128 reads.
__global__ __launch_bounds__(256) void attn_mm(const float* __restrict__ A,
                                               const unsigned short* __restrict__ WhT,
                                               const float* __restrict__ s1,
                                               const float* __restrict__ s2,
                                               const unsigned* __restrict__ s2max_u,
                                               float* __restrict__ pacc,
                                               float* __restrict__ plsum) {
    __shared__ unsigned short Bs[2048 * 8];  // 32 KB, granule-indexed

    const int t = threadIdx.x;
    const int lane = t & 63, wave = t >> 6;
    const int m = lane & 15, q = lane >> 4;
    const int ns = blockIdx.x >> 8;
    const int rg = blockIdx.x & 255;
    const int row0 = rg * 64;
    const int b = row0 >> 11;
    const int nbase = ns * 512;

    const unsigned short* WTb = WhT + (size_t)b * F_OUT * N_DIM;
    const int myrow = row0 + wave * 16 + m;
    const float s1m = s1[myrow];
    const float s2mx = funmap(s2max_u[b]);
    const float xs = s1m + s2mx;
    const float shift = fmaxf(xs, ALPHA * xs);
    const float* Arow = A + (size_t)myrow * N_DIM;
    const float* s2b = s2 + (size_t)b * N_DIM;

    // staging decomposition for thread t, iter i: f = i*256 + t
    const int c_s0 = t >> 6;                  // contributes w to (i*4+w)
    // (c_s, nt_s) computed per-i below

    floatx4 acc[8];
#pragma unroll
    for (int nt = 0; nt < 8; nt++) acc[nt] = (floatx4){0.f, 0.f, 0.f, 0.f};
    float lsum = 0.f;

    for (int tl = 0; tl < TPB; tl++) {
        const int noff = nbase + tl * 128;

        // ---- A + s2 loads first (P-compute waits only on these) ----
        float4 areg[8], zreg[8];
#pragma unroll
        for (int c = 0; c < 4; c++) {
            areg[2 * c] = *(const float4*)(Arow + noff + c * 32 + q * 8);
            areg[2 * c + 1] = *(const float4*)(Arow + noff + c * 32 + q * 8 + 4);
            zreg[2 * c] = *(const float4*)(s2b + noff + c * 32 + q * 8);
            zreg[2 * c + 1] = *(const float4*)(s2b + noff + c * 32 + q * 8 + 4);
        }
        // ---- B-tile loads (stay in flight through P-compute) ----
        uint4 sreg[8];
#pragma unroll
        for (int i = 0; i < 8; i++) {
            int iw = i * 4 + c_s0;           // (i*4 + w)
            int cs = iw & 3, nts = iw >> 2;
            sreg[i] = *(const uint4*)(WTb + (size_t)(nts * 16 + m) * N_DIM + noff + cs * 32 + q * 8);
        }

        // ---- P fragments ----
        short8 pf[4];
#pragma unroll
        for (int c = 0; c < 4; c++) {
            float aa[8] = {areg[2 * c].x, areg[2 * c].y, areg[2 * c].z, areg[2 * c].w,
                           areg[2 * c + 1].x, areg[2 * c + 1].y, areg[2 * c + 1].z, areg[2 * c + 1].w};
            float zz[8] = {zreg[2 * c].x, zreg[2 * c].y, zreg[2 * c].z, zreg[2 * c].w,
                           zreg[2 * c + 1].x, zreg[2 * c + 1].y, zreg[2 * c + 1].z, zreg[2 * c + 1].w};
            union { unsigned short u[8]; short8 v; } pu;
#pragma unroll
            for (int j = 0; j < 8; j++) {
                float x = s1m + zz[j];
                float e = fmaxf(x, ALPHA * x);
                float p = aa[j] * __expf(e - shift);   // A in {0,1} -> exact mask
                unsigned short pb = f2bf(p);
                pu.u[j] = pb;
                lsum += bf2f(pb);
            }
            pf[c] = pu.v;
        }

        // ---- commit B tile to LDS (fragment-major, lane-contiguous writes) ----
#pragma unroll
        for (int i = 0; i < 8; i++)
            *(uint4*)&Bs[(size_t)(i * 256 + t) * 8] = sreg[i];
        __syncthreads();

        // ---- MFMA: stride-1 b128 fragment reads ----
#pragma unroll
        for (int c = 0; c < 4; c++)
#pragma unroll
            for (int nt = 0; nt < 8; nt++) {
                short8 bv = *(const short8*)&Bs[(size_t)((nt * 4 + c) * 64 + lane) * 8];
                acc[nt] = __builtin_amdgcn_mfma_f32_16x16x32_bf16(pf[c], bv, acc[nt], 0, 0, 0);
            }
        __syncthreads();
    }

    // ---- partial outputs ----
    lsum += __shfl_xor(lsum, 16, 64);
    lsum += __shfl_xor(lsum, 32, 64);
    if (q == 0) plsum[(size_t)ns * (B_DIM * N_DIM) + row0 + wave * 16 + m] = lsum;

    float* pa = pacc + (size_t)ns * PS;
#pragma unroll
    for (int r = 0; r < 4; r++) {
        float* prow = pa + (size_t)(row0 + wave * 16 + q * 4 + r) * F_OUT + m;
#pragma unroll
        for (int nt = 0; nt < 8; nt++) prow[nt * 16] = acc[nt][r];
    }
}

// ---------------- Kernel 3: epilogue — sum 4 partials, normalize ----------------
// 2048 blocks x 256 thr; thread = 4 cols of one row (8 rows/block).
__global__ __launch_bounds__(256) void epi(const float* __restrict__ pacc,
                                           const float* __restrict__ plsum,
                                           float* __restrict__ out) {
    const int t = threadIdx.x;
    const int row = blockIdx.x * 8 + (t >> 5);
    const int c0 = (t & 31) * 4;
    float l = 0.f;
#pragma unroll
    for (int ns = 0; ns < NSPLIT; ns++) l += plsum[(size_t)ns * (B_DIM * N_DIM) + row];
    float4 v = make_float4(0.f, 0.f, 0.f, 0.f);
#pragma unroll
    for (int ns = 0; ns < NSPLIT; ns++) {
        float4 p = *(const float4*)(pacc + (size_t)ns * PS + (size_t)row * F_OUT + c0);
        v.x += p.x; v.y += p.y; v.z += p.z; v.w += p.w;
    }
    const float inv = 1.f / l;
    v.x *= inv; v.y *= inv; v.z *= inv; v.w *= inv;
    *(float4*)(out + (size_t)row * F_OUT + c0) = v;
}

extern "C" void kernel_launch(void* const* d_in, const int* in_sizes, int n_in,
                              void* d_out, int out_size, void* d_ws, size_t ws_size,
                              hipStream_t stream) {
    const float* X = (const float*)d_in[0];
    const float* A = (const float*)d_in[1];
    const float* W = (const float*)d_in[2];
    const float* avec = (const float*)d_in[3];
    float* out = (float*)d_out;

    char* ws = (char*)d_ws;
    unsigned short* WhT = (unsigned short*)ws;            ws += PS * 2;            // 4 MB
    float* s1 = (float*)ws;                               ws += B_DIM * N_DIM * 4;
    float* s2 = (float*)ws;                               ws += B_DIM * N_DIM * 4;
    unsigned* s2max_u = (unsigned*)ws;                    ws += 256;
    float* pacc = (float*)ws;                             ws += PS * NSPLIT * 4;   // 32 MB
    float* plsum = (float*)ws;                            // 4 x 64 KB

    hipMemsetAsync(s2max_u, 0, B_DIM * sizeof(unsigned), stream);  // 0 < fmap(any real)
    gemm_xw<<<B_DIM * N_DIM / 64, 256, 0, stream>>>(X, W, avec, WhT, s1, s2, s2max_u);
    attn_mm<<<256 * NSPLIT, 256, 0, stream>>>(A, WhT, s1, s2, s2max_u, pacc, plsum);
    epi<<<B_DIM * N_DIM / 8, 256, 0, stream>>>(pacc, plsum, out);
}